// Round 1
// baseline (170.501 us; speedup 1.0000x reference)
//
#include <hip/hip_runtime.h>
#include <math.h>

// Problem constants (from reference): S=2048, B=64, N=HID=1024.
#define SEQ 2048
#define BB  64
#define NN  1024

// ---------------------------------------------------------------------------
// Kernel 1: u[b][n] = sum_m h[b][m] * W[m][n]
// (scores[b,s] = enc[s,b,:] . u[b,:] + h[b].bias; the bias term is constant
//  per softmax row, so it cancels and is dropped entirely.)
// Grid: 64 b * 8 ntiles = 512 blocks, 128 threads. bid%8 == ntile so blocks
// sharing a W column-slice land on the same XCD (round-robin heuristic) ->
// each XCD's L2 only holds a 512 KB slice of W.
// ---------------------------------------------------------------------------
__global__ __launch_bounds__(128) void proj_kernel(
    const float* __restrict__ h,   // [B][N]
    const float* __restrict__ W,   // [N][N] (m, n)
    float* __restrict__ u)         // [B][N]
{
    const int bid   = blockIdx.x;
    const int ntile = bid & 7;
    const int b     = bid >> 3;
    const int n     = ntile * 128 + threadIdx.x;

    __shared__ float hs[NN];
    for (int m = threadIdx.x; m < NN; m += 128)
        hs[m] = h[b * NN + m];
    __syncthreads();

    float acc = 0.f;
#pragma unroll 8
    for (int m = 0; m < NN; ++m)
        acc = fmaf(hs[m], W[(size_t)m * NN + n], acc);

    u[b * NN + n] = acc;
}

// ---------------------------------------------------------------------------
// Kernel 2 (the 512 MB streamer): scores[b][s] = enc[s][b][:] . u[b][:]
// One wave per (s,b) row; lane i handles float4 chunks j*64+i (coalesced
// 1 KiB per instruction). u rows are 256 KB total -> L2-resident.
// ---------------------------------------------------------------------------
__global__ __launch_bounds__(256) void scores_kernel(
    const float* __restrict__ enc,    // [S][B][N]
    const float* __restrict__ u,      // [B][N]
    float* __restrict__ scores)       // [B][S]
{
    const int gtid   = blockIdx.x * blockDim.x + threadIdx.x;
    const int wave   = gtid >> 6;
    const int lane   = threadIdx.x & 63;
    const int nWaves = (gridDim.x * blockDim.x) >> 6;
    const int totalRows = SEQ * BB;

    for (int row = wave; row < totalRows; row += nWaves) {
        const int b = row & (BB - 1);   // row = s*B + b, B = 64
        const int s = row >> 6;

        const float4* erow = (const float4*)(enc + (size_t)row * NN);
        const float4* urow = (const float4*)(u + (size_t)b * NN);

        float acc = 0.f;
#pragma unroll
        for (int j = 0; j < 4; ++j) {
            float4 e  = erow[j * 64 + lane];
            float4 uu = urow[j * 64 + lane];
            acc += e.x * uu.x + e.y * uu.y + e.z * uu.z + e.w * uu.w;
        }
        // butterfly reduce across the 64-lane wave
#pragma unroll
        for (int off = 32; off > 0; off >>= 1)
            acc += __shfl_xor(acc, off, 64);

        if (lane == 0)
            scores[(size_t)b * SEQ + s] = acc;
    }
}

// ---------------------------------------------------------------------------
// Kernel 3: softmax over s for each b. One block (256 threads) per b.
// ---------------------------------------------------------------------------
__global__ __launch_bounds__(256) void softmax_kernel(
    const float* __restrict__ scores,  // [B][S]
    float* __restrict__ out)           // [B][1][S]
{
    const int b   = blockIdx.x;
    const int tid = threadIdx.x;
    const float* row = scores + (size_t)b * SEQ;

    __shared__ float redmax[4];
    __shared__ float redsum[4];

    float v[8];
    float m = -INFINITY;
#pragma unroll
    for (int j = 0; j < 8; ++j) {
        v[j] = row[j * 256 + tid];
        m = fmaxf(m, v[j]);
    }
#pragma unroll
    for (int off = 32; off > 0; off >>= 1)
        m = fmaxf(m, __shfl_xor(m, off, 64));
    if ((tid & 63) == 0) redmax[tid >> 6] = m;
    __syncthreads();
    m = fmaxf(fmaxf(redmax[0], redmax[1]), fmaxf(redmax[2], redmax[3]));

    float sum = 0.f;
#pragma unroll
    for (int j = 0; j < 8; ++j) {
        v[j] = expf(v[j] - m);
        sum += v[j];
    }
#pragma unroll
    for (int off = 32; off > 0; off >>= 1)
        sum += __shfl_xor(sum, off, 64);
    if ((tid & 63) == 0) redsum[tid >> 6] = sum;
    __syncthreads();
    sum = redsum[0] + redsum[1] + redsum[2] + redsum[3];

    const float inv = 1.f / sum;
#pragma unroll
    for (int j = 0; j < 8; ++j)
        out[(size_t)b * SEQ + j * 256 + tid] = v[j] * inv;
}

// ---------------------------------------------------------------------------
extern "C" void kernel_launch(void* const* d_in, const int* in_sizes, int n_in,
                              void* d_out, int out_size, void* d_ws, size_t ws_size,
                              hipStream_t stream) {
    const float* hidden = (const float*)d_in[0];   // [1][64][1024]
    const float* enc    = (const float*)d_in[1];   // [2048][64][1024]
    const float* W      = (const float*)d_in[2];   // [1024][1024]
    // d_in[3] = bias — cancels under softmax, unused.
    float* out = (float*)d_out;                    // [64][1][2048]

    float* u      = (float*)d_ws;                       // 64*1024 floats = 256 KB
    float* scores = (float*)d_ws + (size_t)BB * NN;     // 64*2048 floats = 512 KB

    proj_kernel<<<BB * 8, 128, 0, stream>>>(hidden, W, u);
    scores_kernel<<<2048, 256, 0, stream>>>(enc, u, scores);
    softmax_kernel<<<BB, 256, 0, stream>>>(scores, out);
}

// Round 2
// 111.180 us; speedup vs baseline: 1.5336x; 1.5336x over previous
//
#include <hip/hip_runtime.h>
#include <math.h>

// Problem constants: S=2048, B=64, N=1024.
#define SEQ 2048
#define BB  64
#define NN  1024
#define MSLICES 4
#define MS (NN / MSLICES)   // 256

// ---------------------------------------------------------------------------
// Kernel 1: partial projection.
//   up[ms][b][n] = sum_{m in slice ms} h[b][m] * W[m][n]
// (bias term is constant per softmax row -> cancels, dropped.)
// Grid: 64 b x 4 ntile x 4 mslice = 1024 blocks, 256 threads (16 waves/CU).
// 4 independent accumulators break the FMA dependency chain.
// ---------------------------------------------------------------------------
__global__ __launch_bounds__(256) void proj_kernel(
    const float* __restrict__ h,   // [B][N]
    const float* __restrict__ W,   // [N][N] (m, n)
    float* __restrict__ up)        // [MSLICES][B][N]
{
    const int tid   = threadIdx.x;
    const int bid   = blockIdx.x;        // b*16 + ntile*4 + ms
    const int ms    = bid & 3;
    const int ntile = (bid >> 2) & 3;
    const int b     = bid >> 4;
    const int n     = ntile * 256 + tid;
    const int m0    = ms * MS;

    __shared__ float hs[MS];
    hs[tid] = h[b * NN + m0 + tid];      // 256 threads, MS == 256
    __syncthreads();

    const float* Wp = W + (size_t)m0 * NN + n;
    float a0 = 0.f, a1 = 0.f, a2 = 0.f, a3 = 0.f;
#pragma unroll 4
    for (int m = 0; m < MS; m += 4) {
        a0 = fmaf(hs[m + 0], Wp[(size_t)(m + 0) * NN], a0);
        a1 = fmaf(hs[m + 1], Wp[(size_t)(m + 1) * NN], a1);
        a2 = fmaf(hs[m + 2], Wp[(size_t)(m + 2) * NN], a2);
        a3 = fmaf(hs[m + 3], Wp[(size_t)(m + 3) * NN], a3);
    }
    up[((size_t)ms * BB + b) * NN + n] = (a0 + a1) + (a2 + a3);
}

// ---------------------------------------------------------------------------
// Kernel 2 (the 512 MB streamer): scores[b][s] = enc[s][b][:] . u[b][:]
// 8192 waves total; wave -> fixed b = wave&63, s0 = wave>>6 in [0,128).
// u[b] = sum of 4 partials, loaded ONCE per wave into 16 VGPRs.
// 2 rows per iteration -> 8 enc float4 loads in flight, reduce amortized.
// ---------------------------------------------------------------------------
__global__ __launch_bounds__(256) void scores_kernel(
    const float* __restrict__ enc,    // [S][B][N]
    const float* __restrict__ up,     // [MSLICES][B][N]
    float* __restrict__ scores)       // [B][S]
{
    const int lane = threadIdx.x & 63;
    const int wave = (blockIdx.x * blockDim.x + threadIdx.x) >> 6; // 0..8191
    const int b    = wave & (BB - 1);
    const int s0   = wave >> 6;                                    // 0..127

    // u[b] into registers: lane's float4 chunks are j*64+lane, j=0..3
    float4 u[4];
#pragma unroll
    for (int j = 0; j < 4; ++j) {
        const size_t idx = (size_t)(j * 64 + lane);
        float4 acc = ((const float4*)(up + (size_t)b * NN))[idx];
#pragma unroll
        for (int ms = 1; ms < MSLICES; ++ms) {
            float4 p = ((const float4*)(up + ((size_t)ms * BB + b) * NN))[idx];
            acc.x += p.x; acc.y += p.y; acc.z += p.z; acc.w += p.w;
        }
        u[j] = acc;
    }

    for (int s = s0; s < SEQ; s += 256) {
        const int s1 = s + 128;
        const float4* e0 = (const float4*)(enc + ((size_t)s  * BB + b) * NN);
        const float4* e1 = (const float4*)(enc + ((size_t)s1 * BB + b) * NN);

        float4 ea[4], eb[4];
#pragma unroll
        for (int j = 0; j < 4; ++j) { ea[j] = e0[j * 64 + lane]; }
#pragma unroll
        for (int j = 0; j < 4; ++j) { eb[j] = e1[j * 64 + lane]; }

        float acc0 = 0.f, acc1 = 0.f;
#pragma unroll
        for (int j = 0; j < 4; ++j) {
            acc0 += ea[j].x * u[j].x + ea[j].y * u[j].y
                  + ea[j].z * u[j].z + ea[j].w * u[j].w;
            acc1 += eb[j].x * u[j].x + eb[j].y * u[j].y
                  + eb[j].z * u[j].z + eb[j].w * u[j].w;
        }
#pragma unroll
        for (int off = 32; off > 0; off >>= 1) {
            acc0 += __shfl_xor(acc0, off, 64);
            acc1 += __shfl_xor(acc1, off, 64);
        }
        if (lane == 0) {
            scores[(size_t)b * SEQ + s]  = acc0;
            scores[(size_t)b * SEQ + s1] = acc1;
        }
    }
}

// ---------------------------------------------------------------------------
// Kernel 3: softmax over s for each b. One block (256 threads) per b.
// ---------------------------------------------------------------------------
__global__ __launch_bounds__(256) void softmax_kernel(
    const float* __restrict__ scores,  // [B][S]
    float* __restrict__ out)           // [B][1][S]
{
    const int b   = blockIdx.x;
    const int tid = threadIdx.x;
    const float* row = scores + (size_t)b * SEQ;

    __shared__ float redmax[4];
    __shared__ float redsum[4];

    float v[8];
    float m = -INFINITY;
#pragma unroll
    for (int j = 0; j < 8; ++j) {
        v[j] = row[j * 256 + tid];
        m = fmaxf(m, v[j]);
    }
#pragma unroll
    for (int off = 32; off > 0; off >>= 1)
        m = fmaxf(m, __shfl_xor(m, off, 64));
    if ((tid & 63) == 0) redmax[tid >> 6] = m;
    __syncthreads();
    m = fmaxf(fmaxf(redmax[0], redmax[1]), fmaxf(redmax[2], redmax[3]));

    float sum = 0.f;
#pragma unroll
    for (int j = 0; j < 8; ++j) {
        v[j] = expf(v[j] - m);
        sum += v[j];
    }
#pragma unroll
    for (int off = 32; off > 0; off >>= 1)
        sum += __shfl_xor(sum, off, 64);
    if ((tid & 63) == 0) redsum[tid >> 6] = sum;
    __syncthreads();
    sum = redsum[0] + redsum[1] + redsum[2] + redsum[3];

    const float inv = 1.f / sum;
#pragma unroll
    for (int j = 0; j < 8; ++j)
        out[(size_t)b * SEQ + j * 256 + tid] = v[j] * inv;
}

// ---------------------------------------------------------------------------
extern "C" void kernel_launch(void* const* d_in, const int* in_sizes, int n_in,
                              void* d_out, int out_size, void* d_ws, size_t ws_size,
                              hipStream_t stream) {
    const float* hidden = (const float*)d_in[0];   // [1][64][1024]
    const float* enc    = (const float*)d_in[1];   // [2048][64][1024]
    const float* W      = (const float*)d_in[2];   // [1024][1024]
    // d_in[3] = bias — cancels under softmax, unused.
    float* out = (float*)d_out;                    // [64][1][2048]

    float* up     = (float*)d_ws;                                  // 4*64*1024 f = 1 MB
    float* scores = (float*)d_ws + (size_t)MSLICES * BB * NN;      // 64*2048 f = 512 KB

    proj_kernel<<<BB * 16, 256, 0, stream>>>(hidden, W, up);
    scores_kernel<<<2048, 256, 0, stream>>>(enc, up, scores);
    softmax_kernel<<<BB, 256, 0, stream>>>(scores, out);
}